// Round 5
// baseline (101.688 us; speedup 1.0000x reference)
//
#include <hip/hip_runtime.h>
#include <hip/hip_bf16.h>

// MLP_small_per_feature: per-feature MLP 1 -> 64 -> 64 -> 1, F=256, B=8192.
// v5: kill the per-pass LDS-pipe dependency chain. Block = 4 waves = 4
// features x 256 rows, grid 2048 (2x oversubscribed). Changes vs v4:
//   - no __shfl_xor reduce: each lane ds_write's its 16-o partial to an LDS
//     plane ob[feat*4+lg][row]; the output tail sums the 4 lane-group
//     partials per row (one-time) instead of 2 serial ds_bpermute per pass.
//   - x staged pass-major xs[w][l15][pass] (stride 20: 16B-aligned,
//     conflict-free); one ds_read_b128 feeds 4 passes.
//   - w2 fragments straight from global (once per wave, reused 16 passes).
//
// MFMA 16x16x32_bf16 layout (verified rounds 1-4, absmax 0.031):
//   A: row m = lane&15, k = (lane>>4)*8 + i
//   B: col n = lane&15, k = (lane>>4)*8 + i
//   C/D: col n = lane&15, row m = (lane>>4)*4 + r

namespace {

constexpr int kF = 256;
constexpr int kH = 64;
constexpr int kB = 8192;

constexpr int kFPB     = 4;               // features per block (one per wave)
constexpr int kRPB     = 256;             // rows per block
constexpr int kThreads = 256;             // 4 waves
constexpr int kFG      = kF / kFPB;       // 64 feature groups
constexpr int kRG      = kB / kRPB;       // 32 row groups
constexpr int kBlocks  = kFG * kRG;       // 2048
constexpr int kPasses  = kRPB / 16;       // 16
constexpr int kQ       = kPasses / 4;     // 4 (ds_read_b128 granules)

constexpr int kXPad = 20;                 // pass-dim stride: 16B-aligned
constexpr int kOPad = kRPB + 1;           // 257: conflict-free tail reads

using f32x4  = __attribute__((ext_vector_type(4))) float;
using bf16x4 = __attribute__((ext_vector_type(4))) __bf16;
using bf16x8 = __attribute__((ext_vector_type(8))) __bf16;

__global__ __launch_bounds__(kThreads, 4)
void mlp_pf_v5(const float* __restrict__ x,
               const float* __restrict__ w1,
               const float* __restrict__ b1,
               const float* __restrict__ w2,
               const float* __restrict__ b2,
               const float* __restrict__ w3,
               const float* __restrict__ b3,
               float* __restrict__ out)
{
  __shared__ float xs[kFPB][16][kXPad];     // 5.1 KB  [feat][l15][pass]
  __shared__ float ob[kFPB * 4][kOPad];     // 16.4 KB [feat*4+lg][row]

  const int tid  = (int)threadIdx.x;
  const int wid  = tid >> 6;
  const int lane = tid & 63;
  const int l15  = lane & 15;
  const int lg   = lane >> 4;

  const int fg = (int)blockIdx.x & (kFG - 1);
  const int rg = (int)blockIdx.x >> 6;
  const int f  = fg * kFPB + wid;           // this wave's feature
  const int r0 = rg * kRPB;

  // ---- w2[f] fragments straight from global (reused 16 passes) ----
  bf16x8 w2frag[4][2];
  {
    const float* w2f = w2 + (size_t)f * (kH * kH);
    #pragma unroll
    for (int t = 0; t < 4; ++t) {
      const int o = t * 16 + l15;
      #pragma unroll
      for (int ks = 0; ks < 2; ++ks) {
        const float* p = w2f + o * kH + ks * 32 + lg * 8;
        const f32x4 lo = *reinterpret_cast<const f32x4*>(p);
        const f32x4 hi = *reinterpret_cast<const f32x4*>(p + 4);
        w2frag[t][ks] = __builtin_shufflevector(
            __builtin_convertvector(lo, bf16x4),
            __builtin_convertvector(hi, bf16x4), 0, 1, 2, 3, 4, 5, 6, 7);
      }
    }
  }

  // ---- stage x tile (256 rows x 4 feats) -> pass-major LDS ----
  {
    const int rr = tid;                    // one row per thread
    const f32x4 v = *reinterpret_cast<const f32x4*>(
        x + (size_t)(r0 + rr) * kF + fg * kFPB);
    const int a = rr & 15, b = rr >> 4;
    xs[0][a][b] = v[0]; xs[1][a][b] = v[1];
    xs[2][a][b] = v[2]; xs[3][a][b] = v[3];
  }

  // ---- per-wave params (tiny, L1/L2-resident) ----
  f32x4 w1v[2][2], b1v[2][2];
  #pragma unroll
  for (int ks = 0; ks < 2; ++ks) {
    const float* pw = w1 + f * kH + ks * 32 + lg * 8;
    const float* pb = b1 + f * kH + ks * 32 + lg * 8;
    w1v[ks][0] = *reinterpret_cast<const f32x4*>(pw);
    w1v[ks][1] = *reinterpret_cast<const f32x4*>(pw + 4);
    b1v[ks][0] = *reinterpret_cast<const f32x4*>(pb);
    b1v[ks][1] = *reinterpret_cast<const f32x4*>(pb + 4);
  }
  f32x4 b2c[4], w3v[4];
  #pragma unroll
  for (int t = 0; t < 4; ++t) {
    b2c[t] = *reinterpret_cast<const f32x4*>(b2 + f * kH + t * 16 + lg * 4);
    w3v[t] = *reinterpret_cast<const f32x4*>(w3 + f * kH + t * 16 + lg * 4);
  }

  __syncthreads();   // xs ready

  const f32x4 zero4 = {0.f, 0.f, 0.f, 0.f};
  float* obp = &ob[wid * 4 + lg][l15];      // per-pass dest: obp[p*16]

  #pragma unroll
  for (int q = 0; q < kQ; ++q) {
    // 4 passes' x values in one conflict-free ds_read_b128
    const f32x4 xq = *reinterpret_cast<const f32x4*>(&xs[wid][l15][q * 4]);

    #pragma unroll
    for (int j = 0; j < 4; ++j) {
      const int p = q * 4 + j;
      const float xv = xq[j];

      // ---- layer 1: h1 = relu(x*w1 + b1) -> bf16 B-fragments ----
      bf16x8 h1frag[2];
      #pragma unroll
      for (int ks = 0; ks < 2; ++ks) {
        f32x4 a = w1v[ks][0] * xv + b1v[ks][0];
        f32x4 b = w1v[ks][1] * xv + b1v[ks][1];
        a = __builtin_elementwise_max(a, zero4);
        b = __builtin_elementwise_max(b, zero4);
        h1frag[ks] = __builtin_shufflevector(
            __builtin_convertvector(a, bf16x4),
            __builtin_convertvector(b, bf16x4), 0, 1, 2, 3, 4, 5, 6, 7);
      }

      // ---- layer 2 (C init = b2) + layer 3 in-lane partial ----
      f32x4 p4 = zero4;
      #pragma unroll
      for (int t = 0; t < 4; ++t) {
        f32x4 acc = __builtin_amdgcn_mfma_f32_16x16x32_bf16(
            w2frag[t][0], h1frag[0], b2c[t], 0, 0, 0);
        acc = __builtin_amdgcn_mfma_f32_16x16x32_bf16(
            w2frag[t][1], h1frag[1], acc, 0, 0, 0);
        const f32x4 r = __builtin_elementwise_max(acc, zero4);
        p4 += r * w3v[t];
      }

      // in-lane partial over this lane-group's 16 o's; no cross-lane ops
      obp[p * 16] = (p4[0] + p4[1]) + (p4[2] + p4[3]);
    }
  }

  __syncthreads();

  // ---- tail: sum 4 lane-group partials per (row, feature), store float4 ----
  {
    const int rr = tid;                    // one row per thread
    const f32x4 b3q = *reinterpret_cast<const f32x4*>(b3 + fg * kFPB);
    f32x4 v;
    #pragma unroll
    for (int w = 0; w < 4; ++w) {
      const float s0 = ob[w * 4 + 0][rr] + ob[w * 4 + 1][rr];
      const float s1 = ob[w * 4 + 2][rr] + ob[w * 4 + 3][rr];
      v[w] = s0 + s1 + b3q[w];
    }
    *reinterpret_cast<f32x4*>(out + (size_t)(r0 + rr) * kF + fg * kFPB) = v;
  }
}

}  // namespace

extern "C" void kernel_launch(void* const* d_in, const int* in_sizes, int n_in,
                              void* d_out, int out_size, void* d_ws, size_t ws_size,
                              hipStream_t stream) {
  const float* x  = (const float*)d_in[0];
  const float* w1 = (const float*)d_in[1];
  const float* b1 = (const float*)d_in[2];
  const float* w2 = (const float*)d_in[3];
  const float* b2 = (const float*)d_in[4];
  const float* w3 = (const float*)d_in[5];
  const float* b3 = (const float*)d_in[6];
  float* out = (float*)d_out;

  hipLaunchKernelGGL(mlp_pf_v5, dim3(kBlocks), dim3(kThreads), 0, stream,
                     x, w1, b1, w2, b2, w3, b3, out);
}